// Round 4
// baseline (479.264 us; speedup 1.0000x reference)
//
#include <hip/hip_runtime.h>

#define N_FEAT 784
#define NF4    196          // N_FEAT / 4
#define N_CLS  10

// Folded network: logits = x @ Weff^T + beff; out = softmax(logits).
// Weff/beff recomputed per block into LDS (inputs L2/L3-hot).
// R0 structure: 256 thr, 16-lane group owns 2 rows, 2 passes.
// New: 2-deep register prefetch pipeline. HBM latency ~900cy; one FMA
// round across 4 waves/SIMD hides ~640cy, so 1-deep stalls ~260cy/iter
// (R0/R3 ~51us vs 33us BW floor). 2-deep = ~1280cy of cover -> no stall.
// Pipeline spans the pass boundary (stage0 at last iter, stage1 before
// the pass-0 reduction) so loads also fly during softmax/store.
__global__ __launch_bounds__(256, 4) void sparse_fused_kernel(
    const float* __restrict__ x,
    const float* __restrict__ Wsp,   // [784,2]
    const float* __restrict__ bsp,   // [784,2]
    const float* __restrict__ fcw,   // [10,784]
    const float* __restrict__ fcb,   // [10]
    float* __restrict__ out)         // [65536,10]
{
    __shared__ float Wl[N_CLS * N_FEAT];   // folded weights, [10][784]
    __shared__ float bl[N_CLS];            // folded bias
    __shared__ float bred[4][N_CLS];

    const int tid  = threadIdx.x;
    const int lane = tid & 63;
    const int wave = tid >> 6;

    // ---- per-block fold of the sparse layer into fc ----
    float bacc[N_CLS];
#pragma unroll
    for (int n = 0; n < N_CLS; ++n) bacc[n] = 0.f;

    for (int i = tid; i < N_FEAT; i += 256) {
        // scatter map from the reference (incl. the i==782 wraparound bug)
        int c0 = (i == 782) ? 0 : i;
        int c1 = (i == 782) ? 1 : ((i == 783) ? 0 : (i + 1));
        float w0 = Wsp[2 * i], w1 = Wsp[2 * i + 1];
        float b0 = bsp[2 * i], b1 = bsp[2 * i + 1];
#pragma unroll
        for (int n = 0; n < N_CLS; ++n) {
            float f0 = fcw[n * N_FEAT + c0];
            float f1 = fcw[n * N_FEAT + c1];
            Wl[n * N_FEAT + i] = f0 * w0 + f1 * w1;
            bacc[n] += f0 * b0 + f1 * b1;
        }
    }
#pragma unroll
    for (int n = 0; n < N_CLS; ++n) {
#pragma unroll
        for (int d = 1; d < 64; d <<= 1)
            bacc[n] += __shfl_xor(bacc[n], d, 64);
    }
    if (lane == 0) {
#pragma unroll
        for (int n = 0; n < N_CLS; ++n) bred[wave][n] = bacc[n];
    }
    __syncthreads();
    if (tid < N_CLS)
        bl[tid] = bred[0][tid] + bred[1][tid] + bred[2][tid] + bred[3][tid] + fcb[tid];
    __syncthreads();

    // ---- main GEMM + softmax ----
    const float4* Wl4 = (const float4*)Wl;
    const int gw = blockIdx.x * 4 + wave;   // global wave id, 0..4095
    const int g  = lane >> 4;               // 16-lane group, 0..3
    const int sl = lane & 15;

    const int rb0 = (gw * 2 + 0) * 8 + g * 2;
    const int rb1 = (gw * 2 + 1) * 8 + g * 2;
    const float4* xa = (const float4*)(x + (size_t)rb0 * N_FEAT);
    const float4* xb = (const float4*)(x + (size_t)rb1 * N_FEAT);

    // tail prefetch index: k4=192..195 for sl<4; clamped in-bounds dummy else
    const int tk4 = (sl < 4) ? (192 + sl) : sl;

    float acc0[N_CLS], acc1[N_CLS];
#pragma unroll
    for (int n = 0; n < N_CLS; ++n) { acc0[n] = 0.f; acc1[n] = 0.f; }

    // pipeline registers: c = consuming stage, p = one stage ahead
    float4 c0, c1, p0, p1;

    // ================= pass 0 =================
    c0 = xa[sl];        c1 = xa[NF4 + sl];          // stage 0
    p0 = xa[sl + 16];   p1 = xa[NF4 + sl + 16];     // stage 1

#pragma unroll
    for (int i = 0; i < 12; ++i) {
        // prefetch stage i+2 (2 rounds ahead of consumption)
        float4 f0, f1;
        if (i < 10)      { f0 = xa[sl + 16 * (i + 2)]; f1 = xa[NF4 + sl + 16 * (i + 2)]; }
        else if (i == 10){ f0 = xa[tk4];               f1 = xa[NF4 + tk4]; }           // tail stage
        else             { f0 = xb[sl];                f1 = xb[NF4 + sl]; }            // pass-1 head
        const int k4 = sl + 16 * i;
#pragma unroll
        for (int n = 0; n < N_CLS; ++n) {
            float4 wv = Wl4[n * NF4 + k4];
            acc0[n] += wv.x * c0.x + wv.y * c0.y + wv.z * c0.z + wv.w * c0.w;
            acc1[n] += wv.x * c1.x + wv.y * c1.y + wv.z * c1.z + wv.w * c1.w;
        }
        c0 = p0; c1 = p1; p0 = f0; p1 = f1;
    }

    // tail FMA (c holds xa[tk4]); p holds pass-1 stage 0
    if (sl < 4) {
        const int k4 = 192 + sl;
#pragma unroll
        for (int n = 0; n < N_CLS; ++n) {
            float4 wv = Wl4[n * NF4 + k4];
            acc0[n] += wv.x * c0.x + wv.y * c0.y + wv.z * c0.z + wv.w * c0.w;
            acc1[n] += wv.x * c1.x + wv.y * c1.y + wv.z * c1.z + wv.w * c1.w;
        }
    }

    // issue pass-1 stage 1 now: flies during reduction + softmax + store
    float4 q0 = xb[sl + 16], q1 = xb[NF4 + sl + 16];

#pragma unroll
    for (int d = 1; d < 16; d <<= 1) {
#pragma unroll
        for (int n = 0; n < N_CLS; ++n) {
            acc0[n] += __shfl_xor(acc0[n], d, 64);
            acc1[n] += __shfl_xor(acc1[n], d, 64);
        }
    }
    {
        float m0 = -1e30f, m1 = -1e30f;
#pragma unroll
        for (int n = 0; n < N_CLS; ++n) {
            acc0[n] += bl[n];
            acc1[n] += bl[n];
            m0 = fmaxf(m0, acc0[n]);
            m1 = fmaxf(m1, acc1[n]);
        }
        float den0 = 0.f, den1 = 0.f;
#pragma unroll
        for (int n = 0; n < N_CLS; ++n) {
            acc0[n] = __expf(acc0[n] - m0);
            acc1[n] = __expf(acc1[n] - m1);
            den0 += acc0[n];
            den1 += acc1[n];
        }
        float inv0 = 1.0f / den0, inv1 = 1.0f / den1;
        float v0 = acc0[0], v1 = acc1[0];
#pragma unroll
        for (int n = 1; n < N_CLS; ++n) {
            v0 = (sl == n) ? acc0[n] : v0;
            v1 = (sl == n) ? acc1[n] : v1;
        }
        if (sl < N_CLS) {
            out[(size_t)rb0 * N_CLS + sl]       = v0 * inv0;
            out[(size_t)(rb0 + 1) * N_CLS + sl] = v1 * inv1;
        }
    }

    // ================= pass 1 =================
#pragma unroll
    for (int n = 0; n < N_CLS; ++n) { acc0[n] = 0.f; acc1[n] = 0.f; }
    c0 = p0; c1 = p1;     // xb stage 0 (issued at pass-0 i==11)
    p0 = q0; p1 = q1;     // xb stage 1 (issued before reduction)

#pragma unroll
    for (int i = 0; i < 12; ++i) {
        float4 f0, f1;
        if (i < 10)      { f0 = xb[sl + 16 * (i + 2)]; f1 = xb[NF4 + sl + 16 * (i + 2)]; }
        else if (i == 10){ f0 = xb[tk4];               f1 = xb[NF4 + tk4]; }           // tail stage
        else             { f0 = xb[sl];                f1 = xb[NF4 + sl]; }            // dummy (L1-hot)
        const int k4 = sl + 16 * i;
#pragma unroll
        for (int n = 0; n < N_CLS; ++n) {
            float4 wv = Wl4[n * NF4 + k4];
            acc0[n] += wv.x * c0.x + wv.y * c0.y + wv.z * c0.z + wv.w * c0.w;
            acc1[n] += wv.x * c1.x + wv.y * c1.y + wv.z * c1.z + wv.w * c1.w;
        }
        c0 = p0; c1 = p1; p0 = f0; p1 = f1;
    }

    if (sl < 4) {
        const int k4 = 192 + sl;
#pragma unroll
        for (int n = 0; n < N_CLS; ++n) {
            float4 wv = Wl4[n * NF4 + k4];
            acc0[n] += wv.x * c0.x + wv.y * c0.y + wv.z * c0.z + wv.w * c0.w;
            acc1[n] += wv.x * c1.x + wv.y * c1.y + wv.z * c1.z + wv.w * c1.w;
        }
    }

#pragma unroll
    for (int d = 1; d < 16; d <<= 1) {
#pragma unroll
        for (int n = 0; n < N_CLS; ++n) {
            acc0[n] += __shfl_xor(acc0[n], d, 64);
            acc1[n] += __shfl_xor(acc1[n], d, 64);
        }
    }
    {
        float m0 = -1e30f, m1 = -1e30f;
#pragma unroll
        for (int n = 0; n < N_CLS; ++n) {
            acc0[n] += bl[n];
            acc1[n] += bl[n];
            m0 = fmaxf(m0, acc0[n]);
            m1 = fmaxf(m1, acc1[n]);
        }
        float den0 = 0.f, den1 = 0.f;
#pragma unroll
        for (int n = 0; n < N_CLS; ++n) {
            acc0[n] = __expf(acc0[n] - m0);
            acc1[n] = __expf(acc1[n] - m1);
            den0 += acc0[n];
            den1 += acc1[n];
        }
        float inv0 = 1.0f / den0, inv1 = 1.0f / den1;
        float v0 = acc0[0], v1 = acc1[0];
#pragma unroll
        for (int n = 1; n < N_CLS; ++n) {
            v0 = (sl == n) ? acc0[n] : v0;
            v1 = (sl == n) ? acc1[n] : v1;
        }
        if (sl < N_CLS) {
            out[(size_t)rb1 * N_CLS + sl]       = v0 * inv0;
            out[(size_t)(rb1 + 1) * N_CLS + sl] = v1 * inv1;
        }
    }
}

extern "C" void kernel_launch(void* const* d_in, const int* in_sizes, int n_in,
                              void* d_out, int out_size, void* d_ws, size_t ws_size,
                              hipStream_t stream) {
    const float* x   = (const float*)d_in[0];   // [65536,784]
    const float* Wsp = (const float*)d_in[1];   // [784,2]
    const float* bsp = (const float*)d_in[2];   // [784,2]
    const float* fcw = (const float*)d_in[3];   // [10,784]
    const float* fcb = (const float*)d_in[4];   // [10]
    float* out = (float*)d_out;                 // [65536,10]

    // 1024 blocks x 256 threads: 4 waves/block, 2 passes x 8 rows per wave
    sparse_fused_kernel<<<1024, 256, 0, stream>>>(x, Wsp, bsp, fcw, fcb, out);
}

// Round 5
// 295.039 us; speedup vs baseline: 1.6244x; 1.6244x over previous
//
#include <hip/hip_runtime.h>

#define N_FEAT 784
#define NF4    196          // N_FEAT / 4
#define N_CLS  10

// Folded network: logits = x @ Weff^T + beff; out = softmax(logits).
// Weff/beff recomputed per block into LDS (7840 fused-FMA, inputs L2/L3-hot).
// Main loop: 16-lane group owns 2 rows; x read directly from global
// (coalesced 256B segments); Weff via conflict-free ds_read_b128 shared
// across both rows. Only 20 live accumulators/lane -> no spills.
// NOTE (session ledger): this exact structure measured 293.5us. Variants
// tried and rejected: 4 rows/group (+3.4us), 512thr/64-VGPR cap (+11us),
// explicit 1-deep prefetch (neutral — compiler already pipelines this),
// 2-deep unrolled pipeline (spill cliff: VGPR=64 + 720MB scratch, +185us).
__global__ __launch_bounds__(256, 4) void sparse_fused_kernel(
    const float* __restrict__ x,
    const float* __restrict__ Wsp,   // [784,2]
    const float* __restrict__ bsp,   // [784,2]
    const float* __restrict__ fcw,   // [10,784]
    const float* __restrict__ fcb,   // [10]
    float* __restrict__ out)         // [65536,10]
{
    __shared__ float Wl[N_CLS * N_FEAT];   // folded weights, [10][784]
    __shared__ float bl[N_CLS];            // folded bias
    __shared__ float bred[4][N_CLS];

    const int tid  = threadIdx.x;
    const int lane = tid & 63;
    const int wave = tid >> 6;

    // ---- per-block fold of the sparse layer into fc ----
    float bacc[N_CLS];
#pragma unroll
    for (int n = 0; n < N_CLS; ++n) bacc[n] = 0.f;

    for (int i = tid; i < N_FEAT; i += 256) {
        // scatter map from the reference (incl. the i==782 wraparound bug)
        int c0 = (i == 782) ? 0 : i;
        int c1 = (i == 782) ? 1 : ((i == 783) ? 0 : (i + 1));
        float w0 = Wsp[2 * i], w1 = Wsp[2 * i + 1];
        float b0 = bsp[2 * i], b1 = bsp[2 * i + 1];
#pragma unroll
        for (int n = 0; n < N_CLS; ++n) {
            float f0 = fcw[n * N_FEAT + c0];
            float f1 = fcw[n * N_FEAT + c1];
            Wl[n * N_FEAT + i] = f0 * w0 + f1 * w1;
            bacc[n] += f0 * b0 + f1 * b1;
        }
    }
#pragma unroll
    for (int n = 0; n < N_CLS; ++n) {
#pragma unroll
        for (int d = 1; d < 64; d <<= 1)
            bacc[n] += __shfl_xor(bacc[n], d, 64);
    }
    if (lane == 0) {
#pragma unroll
        for (int n = 0; n < N_CLS; ++n) bred[wave][n] = bacc[n];
    }
    __syncthreads();
    if (tid < N_CLS)
        bl[tid] = bred[0][tid] + bred[1][tid] + bred[2][tid] + bred[3][tid] + fcb[tid];
    __syncthreads();

    // ---- main GEMM + softmax ----
    const float4* Wl4 = (const float4*)Wl;
    const int gw = blockIdx.x * 4 + wave;   // global wave id, 0..4095
    const int g  = lane >> 4;               // 16-lane group, 0..3
    const int sl = lane & 15;

#pragma unroll
    for (int pass = 0; pass < 2; ++pass) {
        // each wave-pass covers 8 rows: group g owns rows rbase, rbase+1
        const int rbase = (gw * 2 + pass) * 8 + g * 2;
        const float4* xr0 = (const float4*)(x + (size_t)rbase * N_FEAT);
        const float4* xr1 = (const float4*)(x + (size_t)(rbase + 1) * N_FEAT);

        float acc0[N_CLS], acc1[N_CLS];
#pragma unroll
        for (int n = 0; n < N_CLS; ++n) { acc0[n] = 0.f; acc1[n] = 0.f; }

        // lanes stride the 196 float4 features; 12 full steps + tail (sl<4)
        for (int k4 = sl; k4 < NF4; k4 += 16) {
            float4 x0 = xr0[k4];
            float4 x1 = xr1[k4];
#pragma unroll
            for (int n = 0; n < N_CLS; ++n) {
                float4 wv = Wl4[n * NF4 + k4];
                acc0[n] += wv.x * x0.x + wv.y * x0.y + wv.z * x0.z + wv.w * x0.w;
                acc1[n] += wv.x * x1.x + wv.y * x1.y + wv.z * x1.z + wv.w * x1.w;
            }
        }

        // intra-group (16-lane) butterfly; all 4 groups reduce in parallel
#pragma unroll
        for (int d = 1; d < 16; d <<= 1) {
#pragma unroll
            for (int n = 0; n < N_CLS; ++n) {
                acc0[n] += __shfl_xor(acc0[n], d, 64);
                acc1[n] += __shfl_xor(acc1[n], d, 64);
            }
        }

        // fused softmax for both rows (computed redundantly in all 16 lanes)
        float m0 = -1e30f, m1 = -1e30f;
#pragma unroll
        for (int n = 0; n < N_CLS; ++n) {
            acc0[n] += bl[n];
            acc1[n] += bl[n];
            m0 = fmaxf(m0, acc0[n]);
            m1 = fmaxf(m1, acc1[n]);
        }
        float den0 = 0.f, den1 = 0.f;
#pragma unroll
        for (int n = 0; n < N_CLS; ++n) {
            acc0[n] = __expf(acc0[n] - m0);
            acc1[n] = __expf(acc1[n] - m1);
            den0 += acc0[n];
            den1 += acc1[n];
        }
        float inv0 = 1.0f / den0, inv1 = 1.0f / den1;
        float v0 = acc0[0], v1 = acc1[0];
#pragma unroll
        for (int n = 1; n < N_CLS; ++n) {
            v0 = (sl == n) ? acc0[n] : v0;
            v1 = (sl == n) ? acc1[n] : v1;
        }
        if (sl < N_CLS) {
            out[(size_t)rbase * N_CLS + sl]       = v0 * inv0;
            out[(size_t)(rbase + 1) * N_CLS + sl] = v1 * inv1;
        }
    }
}

extern "C" void kernel_launch(void* const* d_in, const int* in_sizes, int n_in,
                              void* d_out, int out_size, void* d_ws, size_t ws_size,
                              hipStream_t stream) {
    const float* x   = (const float*)d_in[0];   // [65536,784]
    const float* Wsp = (const float*)d_in[1];   // [784,2]
    const float* bsp = (const float*)d_in[2];   // [784,2]
    const float* fcw = (const float*)d_in[3];   // [10,784]
    const float* fcb = (const float*)d_in[4];   // [10]
    float* out = (float*)d_out;                 // [65536,10]

    // 1024 blocks x 256 threads: 4 waves/block, 2 passes x 8 rows per wave
    sparse_fused_kernel<<<1024, 256, 0, stream>>>(x, Wsp, bsp, fcw, fcb, out);
}